// Round 1
// baseline (641.015 us; speedup 1.0000x reference)
//
#include <hip/hip_runtime.h>

// MeanAggregator: out[b, :] = mean_k features[neigh_idx[b,k], :]
// U=1e6, D=128, B=1e5, K=10.  Random 512 B gather-reduce.
//
// Layout: 32 lanes per output row, each lane owns one float4 (16 B), so one
// gathered feature row = 32 lanes x 16 B = 512 B, fully coalesced.
//
// R1 change vs 640 us baseline: each 32-lane group now owns ROWS_PT=2 output
// rows -> 20 independent gathers in flight per wave (was 10), idx-load phase
// and wave setup amortized over 2 rows; nontemporal store for `out` (write-
// once, never re-read) to keep L2/L3 capacity for `features` duplicates.

#define AGG_D   128
#define AGG_K   10
#define ROWS_PT 2

typedef float f32x4 __attribute__((ext_vector_type(4)));

__global__ __launch_bounds__(256) void MeanAggregator_43946105372917_kernel(
    const float* __restrict__ features,
    const int*   __restrict__ neigh_idx,
    float*       __restrict__ out,
    int B)
{
    const int tid  = blockIdx.x * blockDim.x + threadIdx.x;
    const int grp  = tid >> 5;            // 32-lane group id
    const int col  = (tid & 31) << 2;     // float4 column offset
    const int row0 = grp * ROWS_PT;
    if (row0 >= B) return;

    // Load all K indices for both rows first so all 20 gathers can be in
    // flight together.  (All 32 lanes of a group read the same 40 B -> one
    // transaction, L1 broadcast.)  Clamp covers a possible odd tail safely.
    int idx[ROWS_PT][AGG_K];
#pragma unroll
    for (int r = 0; r < ROWS_PT; ++r) {
        const int rr = min(row0 + r, B - 1);
        const int* __restrict__ p = neigh_idx + (size_t)rr * (size_t)AGG_K;
#pragma unroll
        for (int k = 0; k < AGG_K; ++k) idx[r][k] = p[k];
    }

    f32x4 acc[ROWS_PT];
#pragma unroll
    for (int r = 0; r < ROWS_PT; ++r) acc[r] = (f32x4)(0.f);

    // 20 independent random-row gathers; k-outer/r-inner so the per-row
    // accumulation chains are interleaved and the compiler can keep many
    // loads outstanding before each dependent add.
#pragma unroll
    for (int k = 0; k < AGG_K; ++k) {
#pragma unroll
        for (int r = 0; r < ROWS_PT; ++r) {
            const f32x4 v = *(const f32x4*)(
                features + ((size_t)(unsigned)idx[r][k] << 7) + col);
            acc[r] += v;
        }
    }

    const float s = 1.0f / (float)AGG_K;
#pragma unroll
    for (int r = 0; r < ROWS_PT; ++r) {
        const int row = row0 + r;
        if (row < B) {
            f32x4 rv = acc[r] * s;
            __builtin_nontemporal_store(
                rv, (f32x4*)(out + (size_t)row * AGG_D + col));
        }
    }
}

extern "C" void kernel_launch(void* const* d_in, const int* in_sizes, int n_in,
                              void* d_out, int out_size, void* d_ws, size_t ws_size,
                              hipStream_t stream) {
    const float* features  = (const float*)d_in[0];
    const int*   neigh_idx = (const int*)d_in[1];
    float*       out       = (float*)d_out;

    const int B = in_sizes[1] / AGG_K;                    // 100000
    const int groups = (B + ROWS_PT - 1) / ROWS_PT;       // 50000
    const int total_threads = groups * 32;
    const int block = 256;
    const int grid  = (total_threads + block - 1) / block;

    MeanAggregator_43946105372917_kernel<<<grid, block, 0, stream>>>(
        features, neigh_idx, out, B);
}

// Round 2
// 640.274 us; speedup vs baseline: 1.0012x; 1.0012x over previous
//
#include <hip/hip_runtime.h>

// MeanAggregator: out[b, :] = mean_k features[neigh_idx[b,k], :]
// U=1e6, D=128, B=1e5, K=10.  Random 512 B gather-reduce.
//
// R2 change: ONE feature row per gather instruction.  Previous layout used
// 32 lanes x float4 per row, so each 64-lane vmem instruction spanned TWO
// discontiguous 512 B rows (possible TA/coalescer split cost).  Now a row is
// read by all 64 lanes as float2 (64 x 8 B = 512 B, single contiguous
// segment per instruction).  Loads in flight per wave kept at 20 (ROWS_PT=2)
// so this isolates segment granularity, not concurrency (R1 already showed
// concurrency is not the limiter: 10->20 KB/wave was exactly null).

#define AGG_D   128
#define AGG_K   10
#define ROWS_PT 2

typedef float f32x2 __attribute__((ext_vector_type(2)));

__global__ __launch_bounds__(256) void MeanAggregator_43946105372917_kernel(
    const float* __restrict__ features,
    const int*   __restrict__ neigh_idx,
    float*       __restrict__ out,
    int B)
{
    const int tid  = blockIdx.x * blockDim.x + threadIdx.x;
    const int grp  = tid >> 6;            // 64-lane group id (one wave)
    const int lane = tid & 63;
    const int col  = lane << 1;           // float2 column offset (0..126)
    const int row0 = grp * ROWS_PT;
    if (row0 >= B) return;

    // All 64 lanes read the same 80 B of indices -> broadcast transactions.
    int idx[ROWS_PT][AGG_K];
#pragma unroll
    for (int r = 0; r < ROWS_PT; ++r) {
        const int rr = min(row0 + r, B - 1);
        const int* __restrict__ p = neigh_idx + (size_t)rr * (size_t)AGG_K;
#pragma unroll
        for (int k = 0; k < AGG_K; ++k) idx[r][k] = p[k];
    }

    f32x2 acc[ROWS_PT];
#pragma unroll
    for (int r = 0; r < ROWS_PT; ++r) acc[r] = (f32x2)(0.f);

    // 20 independent single-segment (512 B) gathers, all in flight before
    // the dependent adds.
#pragma unroll
    for (int k = 0; k < AGG_K; ++k) {
#pragma unroll
        for (int r = 0; r < ROWS_PT; ++r) {
            const f32x2 v = *(const f32x2*)(
                features + ((size_t)(unsigned)idx[r][k] << 7) + col);
            acc[r] += v;
        }
    }

    const float s = 1.0f / (float)AGG_K;
#pragma unroll
    for (int r = 0; r < ROWS_PT; ++r) {
        const int row = row0 + r;
        if (row < B) {
            f32x2 rv = acc[r] * s;
            __builtin_nontemporal_store(
                rv, (f32x2*)(out + (size_t)row * AGG_D + col));
        }
    }
}

extern "C" void kernel_launch(void* const* d_in, const int* in_sizes, int n_in,
                              void* d_out, int out_size, void* d_ws, size_t ws_size,
                              hipStream_t stream) {
    const float* features  = (const float*)d_in[0];
    const int*   neigh_idx = (const int*)d_in[1];
    float*       out       = (float*)d_out;

    const int B = in_sizes[1] / AGG_K;                    // 100000
    const int groups = (B + ROWS_PT - 1) / ROWS_PT;       // 50000 waves
    const long long total_threads = (long long)groups * 64;
    const int block = 256;
    const int grid  = (int)((total_threads + block - 1) / block);

    MeanAggregator_43946105372917_kernel<<<grid, block, 0, stream>>>(
        features, neigh_idx, out, B);
}